// Round 1
// baseline (241.738 us; speedup 1.0000x reference)
//
#include <hip/hip_runtime.h>

// LRMU scan collapsed to: out = U_rev^T @ P, where P[j] = b·A^j built by
// log-doubling (8 sequential steps). All fp32 (no fp32 MFMA on CDNA4, but
// total work is only ~0.37 GFLOP vs 68.7 GFLOP for the naive scan).

#define SEQ_T 256
#define NB 16
#define DIM 128      // IN_DIM == MEM_DIM == 128
#define ORD 256
#define BMROWS 2048  // NB*DIM

// float offsets into workspace
#define OFF_U 0                          // U[t][bm]: 256*2048 = 524288 floats
#define OFF_P (SEQ_T * BMROWS)           // P[j][o]: 256*256
#define OFF_A0 (OFF_P + ORD * ORD)       // A-power ping
#define OFF_A1 (OFF_A0 + ORD * ORD)      // A-power pong
// total: 720896 floats = 2.75 MB of ws

// U[t][bm] = sum_d x[b][t][d] * K[d][m], bm = b*128+m.
// Block handles 4 consecutive t for one b; extra block (blockIdx == NB*64)
// initializes P row 0 = B_mat.
__global__ __launch_bounds__(128) void u_kernel(
    const float* __restrict__ x, const float* __restrict__ K,
    const float* __restrict__ Bm, float* __restrict__ U,
    float* __restrict__ P) {
  int blk = blockIdx.x;
  int m = threadIdx.x;
  if (blk == NB * 64) {  // P[0][:] = b
    P[m] = Bm[m];
    P[DIM + m] = Bm[DIM + m];
    return;
  }
  int b = blk >> 6;
  int tq = blk & 63;  // t = 4*tq .. 4*tq+3
  __shared__ __align__(16) float xs[4][DIM];
#pragma unroll
  for (int r = 0; r < 4; ++r)
    xs[r][m] = x[(b * SEQ_T + tq * 4 + r) * DIM + m];
  __syncthreads();
  float a0 = 0.f, a1 = 0.f, a2 = 0.f, a3 = 0.f;
#pragma unroll 8
  for (int d = 0; d < DIM; ++d) {
    float kv = K[d * DIM + m];  // coalesced; K is L2-resident (64 KB)
    a0 = fmaf(xs[0][d], kv, a0);
    a1 = fmaf(xs[1][d], kv, a1);
    a2 = fmaf(xs[2][d], kv, a2);
    a3 = fmaf(xs[3][d], kv, a3);
  }
  float* Ub = U + b * DIM + m;
  Ub[(tq * 4 + 0) * BMROWS] = a0;
  Ub[(tq * 4 + 1) * BMROWS] = a1;
  Ub[(tq * 4 + 2) * BMROWS] = a2;
  Ub[(tq * 4 + 3) * BMROWS] = a3;
}

// One doubling step k:
//   blocks [0,nsq):    Anew = Aold @ Aold         (squaring; nsq=0 at k=7)
//   blocks [nsq,...):  P[half + r] = P[r] @ Aold  (r in [0, half))
// Tile: 8 rows x 256 cols per block; 256 threads; left tile transposed in
// LDS so per-i fragment is 2x b128 broadcast reads.
__global__ __launch_bounds__(256) void step_kernel(
    const float* __restrict__ Aold, float* __restrict__ Anew,
    float* __restrict__ P, int half, int nsq) {
  __shared__ __align__(16) float ls[ORD][8];  // ls[i][r] = L[r][i], 8 KB
  int blk = blockIdx.x;
  int tid = threadIdx.x;
  const float* L;
  float* C;
  int nrows;
  if (blk < nsq) {
    int r0 = blk * 8;
    L = Aold + r0 * ORD;
    C = Anew + r0 * ORD;
    nrows = 8;
  } else {
    int r0 = (blk - nsq) * 8;
    L = P + r0 * ORD;
    C = P + (half + r0) * ORD;
    nrows = half - r0;
    if (nrows > 8) nrows = 8;
  }
  for (int e = tid; e < 8 * ORD; e += 256) {
    int i = e >> 3, r = e & 7;  // LDS addr == e: conflict-free writes
    ls[i][r] = (r < nrows) ? L[r * ORD + i] : 0.f;
  }
  __syncthreads();
  float acc[8] = {0.f, 0.f, 0.f, 0.f, 0.f, 0.f, 0.f, 0.f};
  int c = tid;
#pragma unroll 4
  for (int i = 0; i < ORD; ++i) {
    float rv = Aold[i * ORD + c];  // coalesced, L2-resident
    const float4 u0 = *(const float4*)&ls[i][0];  // broadcast reads
    const float4 u1 = *(const float4*)&ls[i][4];
    acc[0] = fmaf(u0.x, rv, acc[0]);
    acc[1] = fmaf(u0.y, rv, acc[1]);
    acc[2] = fmaf(u0.z, rv, acc[2]);
    acc[3] = fmaf(u0.w, rv, acc[3]);
    acc[4] = fmaf(u1.x, rv, acc[4]);
    acc[5] = fmaf(u1.y, rv, acc[5]);
    acc[6] = fmaf(u1.z, rv, acc[6]);
    acc[7] = fmaf(u1.w, rv, acc[7]);
  }
  for (int r = 0; r < nrows; ++r) C[r * ORD + c] = acc[r];
}

// out[bm][o] = sum_t U[t][bm] * P[255-t][o]; 8 rows x 256 cols per block.
__global__ __launch_bounds__(256) void out_kernel(
    const float* __restrict__ U, const float* __restrict__ P,
    float* __restrict__ out) {
  __shared__ __align__(16) float us[SEQ_T][8];  // us[t][r], 8 KB
  int bm0 = blockIdx.x * 8;
  int tid = threadIdx.x;
  for (int e = tid; e < SEQ_T * 8; e += 256) {
    int t = e >> 3, r = e & 7;
    us[t][r] = U[t * BMROWS + bm0 + r];
  }
  __syncthreads();
  float acc[8] = {0.f, 0.f, 0.f, 0.f, 0.f, 0.f, 0.f, 0.f};
  int c = tid;
#pragma unroll 4
  for (int t = 0; t < SEQ_T; ++t) {
    float rv = P[(SEQ_T - 1 - t) * ORD + c];
    const float4 u0 = *(const float4*)&us[t][0];
    const float4 u1 = *(const float4*)&us[t][4];
    acc[0] = fmaf(u0.x, rv, acc[0]);
    acc[1] = fmaf(u0.y, rv, acc[1]);
    acc[2] = fmaf(u0.z, rv, acc[2]);
    acc[3] = fmaf(u0.w, rv, acc[3]);
    acc[4] = fmaf(u1.x, rv, acc[4]);
    acc[5] = fmaf(u1.y, rv, acc[5]);
    acc[6] = fmaf(u1.z, rv, acc[6]);
    acc[7] = fmaf(u1.w, rv, acc[7]);
  }
  for (int r = 0; r < 8; ++r) out[(bm0 + r) * ORD + c] = acc[r];
}

extern "C" void kernel_launch(void* const* d_in, const int* in_sizes, int n_in,
                              void* d_out, int out_size, void* d_ws,
                              size_t ws_size, hipStream_t stream) {
  const float* x = (const float*)d_in[0];   // (16,256,128)
  const float* K = (const float*)d_in[1];   // (128,128)
  const float* A = (const float*)d_in[2];   // (256,256)
  const float* Bm = (const float*)d_in[3];  // (256,)
  float* out = (float*)d_out;               // (16, 32768)
  float* ws = (float*)d_ws;
  float* U = ws + OFF_U;
  float* P = ws + OFF_P;
  float* A0 = ws + OFF_A0;
  float* A1 = ws + OFF_A1;

  u_kernel<<<NB * 64 + 1, 128, 0, stream>>>(x, K, Bm, U, P);

  // 8 doubling steps. A-power ping-pong: k=0 reads input A, writes A0;
  // thereafter odd k reads A0/writes A1, even k reads A1/writes A0.
  // k=7 needs no squaring (nsq=0).
  for (int k = 0; k < 8; ++k) {
    const float* Aold = (k == 0) ? A : ((k & 1) ? A0 : A1);
    float* Anew = (k & 1) ? A1 : A0;
    int half = 1 << k;
    int nsq = (k < 7) ? 32 : 0;
    int ndb = (half + 7) / 8;
    step_kernel<<<nsq + ndb, 256, 0, stream>>>(Aold, Anew, P, half, nsq);
  }

  out_kernel<<<BMROWS / 8, 256, 0, stream>>>(U, P, out);
}